// Round 1
// baseline (3743.024 us; speedup 1.0000x reference)
//
#include <hip/hip_runtime.h>

// AudioSNN: 2-layer LIF SNN, reset_mechanism='subtract'.
//   B=4096, T=500, F=40, H=128, O=5. beta=0.9, thr=1.0.
// All membrane arithmetic in f64 to match the numpy (f64) reference's
// Heaviside decisions bit-for-bit (f32 would flip ~tens of spikes).
//
// Mapping: block = 256 threads = 2 batch rows x 128 hidden neurons.
//   - W1 row (40 f64) + W2 column (5 f64) live in registers per thread.
//   - x_t broadcast via LDS, double-buffered (one __syncthreads per step).
//   - layer-2 reduction: 64-lane __shfl_xor butterfly + cross-wave LDS,
//     double-buffered wsum so a single barrier per step suffices.

#define BB 4096
#define TT 500
#define FF 40
#define HH 128
#define OO 5

__global__ __launch_bounds__(256, 2)
void snn_fwd(const float* __restrict__ x, const float* __restrict__ W1,
             const float* __restrict__ b1, const float* __restrict__ W2,
             const float* __restrict__ b2, float* __restrict__ out)
{
    const int tid  = threadIdx.x;
    const int sub  = tid >> 7;       // which of the 2 batch rows
    const int h    = tid & 127;      // hidden neuron
    const int lane = tid & 63;
    const int wid  = tid >> 6;       // wave 0..3 (waves 2*sub, 2*sub+1 belong to batch `sub`)
    const int b    = blockIdx.x * 2 + sub;

    __shared__ double xs[2][2][FF];        // [buf][sub][feat]
    __shared__ double wsum[2][4][8];       // [buf][wave][o] (padded)

    // ---- load weights into registers (f64) ----
    double w[FF];
#pragma unroll
    for (int k = 0; k < FF; ++k) w[k] = (double)W1[h * FF + k];
    const double bb1 = (double)b1[h];
    double w2r[OO];
#pragma unroll
    for (int o = 0; o < OO; ++o) w2r[o] = (double)W2[o * HH + h];
    const double bb2 = (h < OO) ? (double)b2[h] : 0.0;

    double m1 = 0.0, r1 = 0.0;   // layer-1 membrane, previous spike (= reset)
    double m2 = 0.0, r2 = 0.0;   // layer-2 state (threads h<5 only)

    // ---- preload t=0 ----
    if (tid < 2 * FF) {
        const int s2 = tid / FF, f = tid - s2 * FF;
        xs[0][s2][f] = (double)x[((size_t)(blockIdx.x * 2 + s2) * TT + 0) * FF + f];
    }
    __syncthreads();

    for (int t = 0; t < TT; ++t) {
        const int buf = t & 1;

        // prefetch x for t+1 into the other buffer
        if (t + 1 < TT && tid < 2 * FF) {
            const int s2 = tid / FF, f = tid - s2 * FF;
            xs[buf ^ 1][s2][f] =
                (double)x[((size_t)(blockIdx.x * 2 + s2) * TT + (t + 1)) * FF + f];
        }

        // ---- layer 1: cur1 = x_t . W1[h] + b1[h]  (4 independent FMA chains) ----
        double c0 = bb1, c1 = 0.0, c2 = 0.0, c3 = 0.0;
#pragma unroll
        for (int k = 0; k < FF; k += 4) {
            c0 = fma(xs[buf][sub][k + 0], w[k + 0], c0);
            c1 = fma(xs[buf][sub][k + 1], w[k + 1], c1);
            c2 = fma(xs[buf][sub][k + 2], w[k + 2], c2);
            c3 = fma(xs[buf][sub][k + 3], w[k + 3], c3);
        }
        const double cur1 = (c0 + c1) + (c2 + c3);

        m1 = 0.9 * m1 + cur1 - r1;           // thr = 1.0, reset = prev spike
        const bool s1 = (m1 > 1.0);
        r1 = s1 ? 1.0 : 0.0;

        // ---- layer 2 partials: spk1[h] * W2[o][h] ----
        double p0 = s1 ? w2r[0] : 0.0;
        double p1 = s1 ? w2r[1] : 0.0;
        double p2 = s1 ? w2r[2] : 0.0;
        double p3 = s1 ? w2r[3] : 0.0;
        double p4 = s1 ? w2r[4] : 0.0;

#pragma unroll
        for (int off = 32; off >= 1; off >>= 1) {
            p0 += __shfl_xor(p0, off);
            p1 += __shfl_xor(p1, off);
            p2 += __shfl_xor(p2, off);
            p3 += __shfl_xor(p3, off);
            p4 += __shfl_xor(p4, off);
        }
        if (lane == 0) {
            wsum[buf][wid][0] = p0;
            wsum[buf][wid][1] = p1;
            wsum[buf][wid][2] = p2;
            wsum[buf][wid][3] = p3;
            wsum[buf][wid][4] = p4;
        }
        __syncthreads();

        // ---- layer 2 update + output (5 threads per batch row) ----
        if (h < OO) {
            const double cur2 = bb2 + (wsum[buf][sub * 2][h] + wsum[buf][sub * 2 + 1][h]);
            m2 = 0.9 * m2 + cur2 - r2;
            const bool s2v = (m2 > 1.0);
            r2 = s2v ? 1.0 : 0.0;
            out[((size_t)t * BB + b) * OO + h] = s2v ? 1.0f : 0.0f;
        }
        // single barrier per step: wsum/xs are double-buffered
    }
}

extern "C" void kernel_launch(void* const* d_in, const int* in_sizes, int n_in,
                              void* d_out, int out_size, void* d_ws, size_t ws_size,
                              hipStream_t stream)
{
    const float* x  = (const float*)d_in[0];
    const float* W1 = (const float*)d_in[1];
    const float* b1 = (const float*)d_in[2];
    const float* W2 = (const float*)d_in[3];
    const float* b2 = (const float*)d_in[4];
    float* out = (float*)d_out;

    snn_fwd<<<dim3(BB / 2), dim3(256), 0, stream>>>(x, W1, b1, W2, b2, out);
}

// Round 2
// 2290.590 us; speedup vs baseline: 1.6341x; 1.6341x over previous
//
#include <hip/hip_runtime.h>

// AudioSNN: 2-layer LIF SNN (subtract reset). B=4096, T=500, F=40, H=128, O=5.
// f64 recurrence to match the numpy f64 reference's Heaviside decisions
// (R1 verified: absmax 0.0).
//
// R2 mapping: ONE WAVE PER BATCH ROW, lane owns 2 hidden neurons (h=lane, lane+64).
//   - W1 rows in f64 registers (160 VGPR) -> no per-step weight traffic.
//   - x_t addresses are wave-uniform -> scalar loads (SGPR, no VGPR cost).
//   - layer-2 reduction: pure in-wave __shfl_xor butterfly (f64), all lanes
//     end with identical sums -> m2 updated redundantly in-register.
//   - NO LDS, NO __syncthreads: each wave is fully autonomous; 8 independent
//     f64 FMA chains per thread hide FMA latency despite 2 waves/SIMD.

#define BB 4096
#define TT 500
#define FF 40
#define HH 128
#define OO 5

__global__ __launch_bounds__(64, 2)
void snn_fwd(const float* __restrict__ x, const float* __restrict__ W1,
             const float* __restrict__ b1, const float* __restrict__ W2,
             const float* __restrict__ b2, float* __restrict__ out)
{
    const int lane = threadIdx.x;      // 0..63
    const int b    = blockIdx.x;       // batch row

    // ---- weights into registers ----
    double wA[FF], wB[FF];             // W1 rows for h=lane and h=lane+64 (f64)
#pragma unroll
    for (int k = 0; k < FF; ++k) {
        wA[k] = (double)W1[lane * FF + k];
        wB[k] = (double)W1[(lane + 64) * FF + k];
    }
    const double b1A = (double)b1[lane];
    const double b1B = (double)b1[lane + 64];
    float w2A[OO], w2B[OO];            // W2 columns kept f32 (saves 10 VGPR), cvt on use
#pragma unroll
    for (int o = 0; o < OO; ++o) {
        w2A[o] = W2[o * HH + lane];
        w2B[o] = W2[o * HH + lane + 64];
    }
    double b2r[OO];                    // uniform -> compiler should scalarize
#pragma unroll
    for (int o = 0; o < OO; ++o) b2r[o] = (double)b2[o];

    const float* __restrict__ xrow = x + (size_t)b * TT * FF;

    double m1A = 0.0, m1B = 0.0;
    double m2[OO];
#pragma unroll
    for (int o = 0; o < OO; ++o) m2[o] = 0.0;

    for (int t = 0; t < TT; ++t) {
        const float* xt = xrow + t * FF;   // wave-uniform address -> s_load

        // ---- layer 1: two dot products, 8 independent FMA chains ----
        double a0 = b1A, a1 = 0.0, a2 = 0.0, a3 = 0.0;
        double c0 = b1B, c1 = 0.0, c2 = 0.0, c3 = 0.0;
#pragma unroll
        for (int k = 0; k < FF; k += 4) {
            const double x0 = (double)xt[k + 0];
            const double x1 = (double)xt[k + 1];
            const double x2 = (double)xt[k + 2];
            const double x3 = (double)xt[k + 3];
            a0 = fma(x0, wA[k + 0], a0);  c0 = fma(x0, wB[k + 0], c0);
            a1 = fma(x1, wA[k + 1], a1);  c1 = fma(x1, wB[k + 1], c1);
            a2 = fma(x2, wA[k + 2], a2);  c2 = fma(x2, wB[k + 2], c2);
            a3 = fma(x3, wA[k + 3], a3);  c3 = fma(x3, wB[k + 3], c3);
        }
        const double cur1A = (a0 + a1) + (a2 + a3);
        const double cur1B = (c0 + c1) + (c2 + c3);

        // ---- layer-1 membrane (reset recomputed from previous m) ----
        const double rstA = (m1A > 1.0) ? 1.0 : 0.0;
        const double rstB = (m1B > 1.0) ? 1.0 : 0.0;
        m1A = 0.9 * m1A + cur1A - rstA;
        m1B = 0.9 * m1B + cur1B - rstB;
        const bool sA = (m1A > 1.0);
        const bool sB = (m1B > 1.0);

        // ---- layer-2 partials + in-wave butterfly reduction (f64) ----
        double p[OO];
#pragma unroll
        for (int o = 0; o < OO; ++o)
            p[o] = (sA ? (double)w2A[o] : 0.0) + (sB ? (double)w2B[o] : 0.0);

#pragma unroll
        for (int off = 32; off >= 1; off >>= 1) {
#pragma unroll
            for (int o = 0; o < OO; ++o) p[o] += __shfl_xor(p[o], off, 64);
        }
        // xor butterfly: all lanes hold bit-identical sums (commutative pairs)

        // ---- layer-2 membrane, redundantly in every lane ----
#pragma unroll
        for (int o = 0; o < OO; ++o) {
            const double rst = (m2[o] > 1.0) ? 1.0 : 0.0;
            m2[o] = 0.9 * m2[o] + (p[o] + b2r[o]) - rst;
        }

        // ---- output: lanes 0..4 write spk2 (static-index select, rule #20) ----
        double msel = m2[0];
#pragma unroll
        for (int o = 1; o < OO; ++o) msel = (lane == o) ? m2[o] : msel;
        if (lane < OO)
            out[((size_t)t * BB + b) * OO + lane] = (msel > 1.0) ? 1.0f : 0.0f;
    }
}

extern "C" void kernel_launch(void* const* d_in, const int* in_sizes, int n_in,
                              void* d_out, int out_size, void* d_ws, size_t ws_size,
                              hipStream_t stream)
{
    const float* x  = (const float*)d_in[0];
    const float* W1 = (const float*)d_in[1];
    const float* b1 = (const float*)d_in[2];
    const float* W2 = (const float*)d_in[3];
    const float* b2 = (const float*)d_in[4];
    float* out = (float*)d_out;

    snn_fwd<<<dim3(BB), dim3(64), 0, stream>>>(x, W1, b1, W2, b2, out);
}